// Round 8
// baseline (103.129 us; speedup 1.0000x reference)
//
#include <hip/hip_runtime.h>
#include <cstdint>
#include <cstddef>

#define BB 4
#define CC 256
#define NN 4096
#define CO 32

typedef __attribute__((ext_vector_type(8))) short bf8;
typedef __attribute__((ext_vector_type(4))) float f4;
typedef __attribute__((ext_vector_type(16))) float f16f;
typedef __attribute__((ext_vector_type(2))) unsigned int u32x2;

#define AS1 __attribute__((address_space(1)))
#define AS3 __attribute__((address_space(3)))

__device__ __forceinline__ unsigned short f2bf(float f) {
    union { float f; unsigned int u; } c; c.f = f;
    unsigned int r = c.u + 0x7FFFu + ((c.u >> 16) & 1u);
    return (unsigned short)(r >> 16);
}
__device__ __forceinline__ float bf2f(unsigned short b) {
    union { unsigned int u; float f; } c; c.u = ((unsigned int)b) << 16;
    return c.f;
}
__device__ __forceinline__ unsigned int cvt_pk_bf16(float a, float b) {
    unsigned int r;
    asm("v_cvt_pk_bf16_f32 %0, %1, %2" : "=v"(r) : "v"(a), "v"(b));
    return r;
}

// ---------------- kernel 1: fused prep (transpose + QK-proj + V-proj) -------
__global__ __launch_bounds__(512, 2) void k_prep(
        const float* __restrict__ x,
        const float* __restrict__ wq, const float* __restrict__ bq,
        const float* __restrict__ wk, const float* __restrict__ bk,
        const float* __restrict__ wv, const float* __restrict__ bv,
        unsigned short* __restrict__ q_hi, unsigned short* __restrict__ q_lo,
        unsigned short* __restrict__ k_hi, unsigned short* __restrict__ k_lo,
        unsigned short* __restrict__ vws) {
    __shared__ float xT[64 * 256];   // (i,c) at i*256 + ((c>>2)^(i&7))*4 + (c&3)
    int blk = blockIdx.x;
    int it = blk & 63, b = blk >> 6;
    int i0 = it * 64;
    int tid = threadIdx.x, w = tid >> 6, lane = tid & 63;
    int lr = lane & 15, lg = lane >> 4;

    // phase 1: load + swizzled transpose
    {
        const float* xp = x + (size_t)b * CC * NN + i0;
        int cl = tid >> 4;            // 0..31
        int il = (tid & 15) * 4;      // 0..60
#pragma unroll
        for (int pass = 0; pass < 8; ++pass) {
            int c = pass * 32 + cl;
            f4 v = *(const f4*)(xp + (size_t)c * NN + il);
#pragma unroll
            for (int jj = 0; jj < 4; ++jj) {
                int i = il + jj;
                xT[i * 256 + (((c >> 2) ^ (i & 7)) << 2) + (c & 3)] = v[jj];
            }
        }
    }
    __syncthreads();

    if (w < 4) {
        // ---- Q/K projection, wave w -> local i rows [w*16, w*16+16) ----
        f4 acc[4] = {};
        for (int ks = 0; ks < 8; ++ks) {
            int i = w * 16 + lr;
            int kc = ks * 32 + lg * 8;
            f4 xa = *(const f4*)&xT[i * 256 + (((kc >> 2) ^ (i & 7)) << 2)];
            f4 xb = *(const f4*)&xT[i * 256 + ((((kc >> 2) + 1) ^ (i & 7)) << 2)];
            bf8 ahi, alo;
#pragma unroll
            for (int e = 0; e < 8; ++e) {
                float f = (e < 4) ? xa[e] : xb[e - 4];
                unsigned short hh = f2bf(f);
                ahi[e] = (short)hh;
                alo[e] = (short)f2bf(f - bf2f(hh));
            }
#pragma unroll
            for (int u = 0; u < 4; ++u) {
                int o = u * 16 + lr;
                const float* wrow = (u < 2) ? (wq + (size_t)o * CC)
                                            : (wk + (size_t)(o - 32) * CC);
                bf8 bhi, blo;
#pragma unroll
                for (int e = 0; e < 8; ++e) {
                    float wvv = wrow[ks * 32 + lg * 8 + e];
                    unsigned short hh = f2bf(wvv);
                    bhi[e] = (short)hh;
                    blo[e] = (short)f2bf(wvv - bf2f(hh));
                }
                acc[u] = __builtin_amdgcn_mfma_f32_16x16x32_bf16(alo, bhi, acc[u], 0, 0, 0);
                acc[u] = __builtin_amdgcn_mfma_f32_16x16x32_bf16(ahi, blo, acc[u], 0, 0, 0);
                acc[u] = __builtin_amdgcn_mfma_f32_16x16x32_bf16(ahi, bhi, acc[u], 0, 0, 0);
            }
        }
#pragma unroll
        for (int u = 0; u < 4; ++u) {
            int o = u * 16 + lr;
            float bias = (u < 2) ? bq[o] : bk[o - 32];
#pragma unroll
            for (int r = 0; r < 4; ++r) {
                int i = i0 + w * 16 + lg * 4 + r;
                float v = acc[u][r] + bias;
                unsigned short hh = f2bf(v);
                unsigned short ll = f2bf(v - bf2f(hh));
                if (u < 2) {
                    size_t off = ((size_t)b * NN + i) * CO + o;
                    q_hi[off] = hh; q_lo[off] = ll;
                } else {
                    size_t off = ((size_t)b * NN + i) * CO + (o - 32);
                    k_hi[off] = hh; k_lo[off] = ll;
                }
            }
        }
    } else {
        // ---- V projection, wave (w-4) -> c rows [(w-4)*64, +64) ----
        int cb = (w - 4) * 64;
        f4 acc[4][4];   // [u c-sub][t i-sub]
#pragma unroll
        for (int u = 0; u < 4; ++u) {
            f4 bias4;
#pragma unroll
            for (int r = 0; r < 4; ++r) bias4[r] = bv[cb + u * 16 + lg * 4 + r];
#pragma unroll
            for (int t = 0; t < 4; ++t) acc[u][t] = bias4;
        }
        for (int ks = 0; ks < 8; ++ks) {
            bf8 bfr[4];
#pragma unroll
            for (int t = 0; t < 4; ++t) {
                int i = t * 16 + lr;
                int kc = ks * 32 + lg * 8;
                f4 xa = *(const f4*)&xT[i * 256 + (((kc >> 2) ^ (i & 7)) << 2)];
                f4 xb = *(const f4*)&xT[i * 256 + ((((kc >> 2) + 1) ^ (i & 7)) << 2)];
#pragma unroll
                for (int e = 0; e < 8; ++e)
                    bfr[t][e] = (short)f2bf((e < 4) ? xa[e] : xb[e - 4]);
            }
#pragma unroll
            for (int u = 0; u < 4; ++u) {
                const float* wrow = wv + (size_t)(cb + u * 16 + lr) * CC + ks * 32 + lg * 8;
                bf8 afr;
#pragma unroll
                for (int e = 0; e < 8; ++e) afr[e] = (short)f2bf(wrow[e]);
#pragma unroll
                for (int t = 0; t < 4; ++t)
                    acc[u][t] = __builtin_amdgcn_mfma_f32_16x16x32_bf16(afr, bfr[t], acc[u][t], 0, 0, 0);
            }
        }
#pragma unroll
        for (int u = 0; u < 4; ++u)
#pragma unroll
            for (int t = 0; t < 4; ++t)
#pragma unroll
                for (int r = 0; r < 4; ++r) {
                    int c = cb + u * 16 + lg * 4 + r;
                    vws[((size_t)b * CC + c) * NN + i0 + t * 16 + lr] = f2bf(acc[u][t][r]);
                }
    }
}

// ---------------- kernel 2: flash attention + residual ----------------
// 512 blocks (2/CU), 8 waves. Block = (batch, 64q, 128c-half).
// 32x32x16 MFMA. S computed ONCE (waves 0-3: jh=w&1, qh=w>>1, in-register
// softmax via swapped QK^T, P to LDS). All 8 waves PV: (cs=w&3, qh'=w>>2)
// owns a 32c x 32q output tile, contracting full 64-j per iter.
// ONE barrier/iter: lgkm(0) + counted vmcnt(1).
//   K2 triple-buffer: staged 2 ahead (pre-barrier), read pre-barrier.
//   Vt double-buffer: staged post-barrier, read after NEXT barrier.
//   P2 double-buffer: written pre-barrier, read post-barrier.
__global__ __launch_bounds__(512, 4) void k_attn(
        const unsigned short* __restrict__ q_hi, const unsigned short* __restrict__ q_lo,
        const unsigned short* __restrict__ k_hi, const unsigned short* __restrict__ k_lo,
        const unsigned short* __restrict__ vws,
        const float* __restrict__ x, float* __restrict__ out) {
    __shared__ __align__(16) unsigned short Vt[2][8192];    // [c 128][slot 8][8]
    __shared__ __align__(16) unsigned short K2[3][4096];    // [j 64][slot 8][8] hi0-3/lo4-7
    __shared__ __align__(16) unsigned short P2[2][2][2048]; // [buf][qh][q 32][slot 8][8]
    __shared__ float lsum_s[2][2][32];                      // [qh][jh][q]

    int m = blockIdx.x;
    int xcd = m & 7;                 // XCD pair {2b,2b+1} serves batch b
    int b = xcd >> 1;
    int t128 = ((m >> 3) << 1) + (xcd & 1);
    int qblk = t128 >> 1;            // 0..63
    int hc = t128 & 1;               // c-half
    int i0 = qblk * 64;
    int cb0 = hc * 128;
    int tid = threadIdx.x, w = tid >> 6, lane = tid & 63;
    int l31 = lane & 31, h = lane >> 5;
    int fsw = (lane & 7) ^ ((lane >> 3) & 3);   // slot swizzle for rows = l&31
    int jh = w & 1, qh = w >> 1;     // S roles (valid for w<4)
    int cs = w & 3, qhp = w >> 2;    // PV roles

    // Q fragments (S-waves only): lane holds Q[q = qh*32+l31][d = dc*16+h*8+e]
    bf8 qfh[2], qfl[2];
    if (w < 4) {
        size_t qoff = ((size_t)b * NN + i0 + qh * 32 + l31) * CO + h * 8;
        qfh[0] = *(const bf8*)(q_hi + qoff);
        qfl[0] = *(const bf8*)(q_lo + qoff);
        qfh[1] = *(const bf8*)(q_hi + qoff + 16);
        qfl[1] = *(const bf8*)(q_lo + qoff + 16);
    }

    const unsigned short* vrow = vws + (size_t)b * CC * NN;
    // stage sources (pre-swizzled so linear LDS dest + swizzled reads agree)
    int l3 = lane >> 3, sl = lane & 7;
    int usV0 = sl ^ l3 ^ ((2 * w) & 3);
    int usV1 = usV0 ^ 1;
    const unsigned short* vsrc0 = vrow + (size_t)(cb0 + w * 16 + l3) * NN + usV0 * 8;
    const unsigned short* vsrc1 = vrow + (size_t)(cb0 + w * 16 + 8 + l3) * NN + usV1 * 8;
    int usK = sl ^ l3 ^ (w & 3);
    const unsigned short* kbase = (usK < 4) ? (k_hi + (size_t)b * NN * CO + usK * 8)
                                            : (k_lo + (size_t)b * NN * CO + (usK - 4) * 8);
    const unsigned short* ksrc = kbase + (size_t)(w * 8 + l3) * CO;

    auto stageV = [&](int jt, int p) {
        int j0 = ((jt < 64) ? jt : 63) * 64;
        __builtin_amdgcn_global_load_lds((const AS1 void*)(vsrc0 + j0),
            (AS3 void*)(&Vt[p][(w * 16) * 64]), 16, 0, 0);
        __builtin_amdgcn_global_load_lds((const AS1 void*)(vsrc1 + j0),
            (AS3 void*)(&Vt[p][(w * 16 + 8) * 64]), 16, 0, 0);
    };
    auto stageK = [&](int jt, int p) {
        int j0 = ((jt < 64) ? jt : 63) * 64;
        __builtin_amdgcn_global_load_lds((const AS1 void*)(ksrc + (size_t)j0 * CO),
            (AS3 void*)(&K2[p][(w * 8) * 64]), 16, 0, 0);
    };

    f16f acc = {};
    float lsum = 0.f;

    stageV(0, 0); stageK(0, 0); stageK(1, 1);
    __syncthreads();

    for (int jt = 0; jt < 64; ++jt) {
        int pv = jt & 1;
        int pk = jt % 3;
        if (w < 4) {
            // ---- S = K·Q^T (32x32x16, split precision) + exp + pack P ----
            const unsigned short* Kp = &K2[pk][(jh * 32 + l31) * 64];
            f16f s = {};
#pragma unroll
            for (int dc = 0; dc < 2; ++dc) {
                bf8 kfh = *(const bf8*)(Kp + (((2 * dc + h) ^ fsw) * 8));
                bf8 kfl = *(const bf8*)(Kp + (((4 + 2 * dc + h) ^ fsw) * 8));
                s = __builtin_amdgcn_mfma_f32_32x32x16_bf16(kfh, qfl[dc], s, 0, 0, 0);
                s = __builtin_amdgcn_mfma_f32_32x32x16_bf16(kfl, qfh[dc], s, 0, 0, 0);
                s = __builtin_amdgcn_mfma_f32_32x32x16_bf16(kfh, qfh[dc], s, 0, 0, 0);
            }
            unsigned int pk32[8];
#pragma unroll
            for (int i = 0; i < 8; ++i) {
                float e0 = __expf(s[2 * i]), e1 = __expf(s[2 * i + 1]);
                lsum += e0 + e1;
                pk32[i] = cvt_pk_bf16(e0, e1);
            }
            // write P^T rows q=l31: pair-group g -> j_local {8g+4h..+3}
            unsigned short* Pp = &P2[pv][qh][l31 * 64 + h * 4];
#pragma unroll
            for (int g = 0; g < 4; ++g) {
                u32x2 d2; d2[0] = pk32[2 * g]; d2[1] = pk32[2 * g + 1];
                *(u32x2*)(Pp + (((jh * 4 + g) ^ fsw) * 8)) = d2;
            }
        }
        stageK(jt + 2, (jt + 2) % 3);
        // ---- ONE barrier: P2 visible; V(jt)/K(jt+1) drained; K(jt+2) in flight
        __builtin_amdgcn_sched_barrier(0);
        asm volatile("s_waitcnt vmcnt(1) lgkmcnt(0)" ::: "memory");
        __builtin_amdgcn_s_barrier();
        __builtin_amdgcn_sched_barrier(0);
        // ---- PV: acc += V-tile(A) x P(B), full 64-j contraction ----
        __builtin_amdgcn_s_setprio(1);
        {
            const unsigned short* Pr = &P2[pv][qhp][l31 * 64];
            const unsigned short* Vr = &Vt[pv][(cs * 32 + l31) * 64];
#pragma unroll
            for (int kc = 0; kc < 4; ++kc) {
                bf8 pb = *(const bf8*)(Pr + (((2 * kc + h) ^ fsw) * 8));
                bf8 vf = *(const bf8*)(Vr + (((2 * kc + h) ^ fsw) * 8));
                acc = __builtin_amdgcn_mfma_f32_32x32x16_bf16(vf, pb, acc, 0, 0, 0);
            }
        }
        __builtin_amdgcn_s_setprio(0);
        stageV(jt + 1, pv ^ 1);      // post-barrier: WAR-safe, drains next barrier
    }

    // denominator: lane covers (q=l31, jh, h-subset); h-halves combine in-wave
    lsum += __shfl_xor(lsum, 32, 64);
    if (w < 4 && lane < 32) lsum_s[qh][jh][l31] = lsum;
    __syncthreads();

    // epilogue: O^T * linv + residual
    float linv = 1.0f / (lsum_s[qhp][0][l31] + lsum_s[qhp][1][l31]);
    int iq = i0 + qhp * 32 + l31;
#pragma unroll
    for (int r = 0; r < 16; ++r) {
        int c = cb0 + cs * 32 + (r & 3) + 8 * (r >> 2) + 4 * h;
        size_t off = ((size_t)(b * CC + c)) * NN + iq;
        out[off] = acc[r] * linv + x[off];
    }
}

extern "C" void kernel_launch(void* const* d_in, const int* in_sizes, int n_in,
                              void* d_out, int out_size, void* d_ws, size_t ws_size,
                              hipStream_t stream) {
    const float* x  = (const float*)d_in[0];
    const float* wq = (const float*)d_in[1];
    const float* bq = (const float*)d_in[2];
    const float* wk = (const float*)d_in[3];
    const float* bk = (const float*)d_in[4];
    const float* wv = (const float*)d_in[5];
    const float* bv = (const float*)d_in[6];
    float* out = (float*)d_out;
    char* ws = (char*)d_ws;
    // ws: qh 1MB | ql 1MB | kh 1MB | kl 1MB | v 8MB
    unsigned short* qh = (unsigned short*)(ws);
    unsigned short* ql = (unsigned short*)(ws + 1048576);
    unsigned short* kh = (unsigned short*)(ws + 2097152);
    unsigned short* kl = (unsigned short*)(ws + 3145728);
    unsigned short* vv = (unsigned short*)(ws + 4194304);

    hipLaunchKernelGGL(k_prep, dim3(256), dim3(512), 0, stream,
                       x, wq, bq, wk, bk, wv, bv, qh, ql, kh, kl, vv);
    hipLaunchKernelGGL(k_attn, dim3(512), dim3(512), 0, stream,
                       qh, ql, kh, kl, vv, x, out);
}